// Round 1
// baseline (1093.348 us; speedup 1.0000x reference)
//
#include <hip/hip_runtime.h>
#include <math.h>

#define TSEQ 2048
#define CEMB 1024
#define NHEAD 16
#define HS 64

// ---------------- RoPE table ----------------
// Reference quirk: _apply_rope uses cache[:d1] where d1 = n_head after the
// transpose, so the rotation angle is head_index * theta_j (constant over t).
__global__ void rope_tbl_k(float* __restrict__ tbl) {
    int i = blockIdx.x * blockDim.x + threadIdx.x;
    if (i >= NHEAD * 32) return;
    int h = i >> 5, j = i & 31;
    double theta = pow(10000.0, -2.0 * (double)j / 1024.0);
    double ang = (double)h * theta;
    tbl[2 * i + 0] = (float)cos(ang);
    tbl[2 * i + 1] = (float)sin(ang);
}

// ---------------- QKV GEMM + bias + RoPE epilogue ----------------
// X: (4096, 1024), W: (1024, 3072). Tile 64x64, BK=16, 256 thr, 4x4 microtile.
__global__ __launch_bounds__(256) void qkv_gemm_k(
    const float* __restrict__ X, const float* __restrict__ W,
    const float* __restrict__ bias, const float* __restrict__ tbl,
    float* __restrict__ Qd, float* __restrict__ Kd, float* __restrict__ Vd)
{
    __shared__ float As[16][68];
    __shared__ float Bs[16][68];
    const int tid = threadIdx.x;
    const int n0 = blockIdx.x * 64;   // 0..3071
    const int m0 = blockIdx.y * 64;   // 0..4095
    const int tm = tid >> 4, tn = tid & 15;
    const int lr = tid >> 2, lc = tid & 3;    // A-load: row, k-float4
    const int bk = tid >> 4, bc = tid & 15;   // B-load: k, col-float4
    const float* Arow = X + (size_t)(m0 + lr) * CEMB + lc * 4;
    const float* Brow = W + (size_t)bk * (3 * CEMB) + n0 + bc * 4;
    float acc[4][4] = {};
    for (int k0 = 0; k0 < CEMB; k0 += 16) {
        float4 a = *(const float4*)(Arow + k0);
        As[lc * 4 + 0][lr] = a.x; As[lc * 4 + 1][lr] = a.y;
        As[lc * 4 + 2][lr] = a.z; As[lc * 4 + 3][lr] = a.w;
        *(float4*)&Bs[bk][bc * 4] = *(const float4*)(Brow + (size_t)k0 * (3 * CEMB));
        __syncthreads();
#pragma unroll
        for (int k = 0; k < 16; ++k) {
            float4 av = *(const float4*)&As[k][tm * 4];
            float4 bv = *(const float4*)&Bs[k][tn * 4];
            acc[0][0] += av.x * bv.x; acc[0][1] += av.x * bv.y;
            acc[0][2] += av.x * bv.z; acc[0][3] += av.x * bv.w;
            acc[1][0] += av.y * bv.x; acc[1][1] += av.y * bv.y;
            acc[1][2] += av.y * bv.z; acc[1][3] += av.y * bv.w;
            acc[2][0] += av.z * bv.x; acc[2][1] += av.z * bv.y;
            acc[2][2] += av.z * bv.z; acc[2][3] += av.z * bv.w;
            acc[3][0] += av.w * bv.x; acc[3][1] += av.w * bv.y;
            acc[3][2] += av.w * bv.z; acc[3][3] += av.w * bv.w;
        }
        __syncthreads();
    }
    // epilogue: bias + rope, scatter to (B, nh, T, hs)
    const int sec = n0 >> 10;            // 0=q 1=k 2=v (uniform per block)
    const int h = (n0 & 1023) >> 6;      // uniform per block
    const int dbase = tn * 4;            // hs-dim base (n0 % 64 == 0)
    const int j0 = dbase >> 1;
    const float c0 = tbl[(h * 32 + j0) * 2 + 0], s0 = tbl[(h * 32 + j0) * 2 + 1];
    const float c1 = tbl[(h * 32 + j0 + 1) * 2 + 0], s1 = tbl[(h * 32 + j0 + 1) * 2 + 1];
    const float b0 = bias[n0 + dbase + 0], b1 = bias[n0 + dbase + 1];
    const float b2 = bias[n0 + dbase + 2], b3 = bias[n0 + dbase + 3];
    float* dst = (sec == 0) ? Qd : (sec == 1) ? Kd : Vd;
#pragma unroll
    for (int i = 0; i < 4; ++i) {
        int mrow = m0 + tm * 4 + i;
        int bb = mrow >> 11, t = mrow & 2047;
        float v0 = acc[i][0] + b0, v1 = acc[i][1] + b1;
        float v2 = acc[i][2] + b2, v3 = acc[i][3] + b3;
        float4 o;
        if (sec < 2) {
            o.x = v0 * c0 - v1 * s0; o.y = v1 * c0 + v0 * s0;
            o.z = v2 * c1 - v3 * s1; o.w = v3 * c1 + v2 * s1;
        } else { o.x = v0; o.y = v1; o.z = v2; o.w = v3; }
        *(float4*)&dst[((size_t)(bb * NHEAD + h) * TSEQ + t) * HS + dbase] = o;
    }
}

// ---------------- Flash attention (fp32) ----------------
// Block: 32 q-rows, K-tiles of 64. 256 thr: row = tid>>3, cq = tid&7.
__global__ __launch_bounds__(256) void attn_k(
    const float* __restrict__ Q, const float* __restrict__ K,
    const float* __restrict__ V, float* __restrict__ Y)
{
    __shared__ float Qs[32][68];
    __shared__ float Ks[64][68];
    __shared__ float Vs[64][68];
    __shared__ float Ps[32][65];
    const int tid = threadIdx.x;
    const int qt = blockIdx.x;   // 0..63
    const int bh = blockIdx.y;   // 0..31
    const float* Qp = Q + (size_t)bh * TSEQ * HS;
    const float* Kp = K + (size_t)bh * TSEQ * HS;
    const float* Vp = V + (size_t)bh * TSEQ * HS;
    const int row = tid >> 3, cq = tid & 7;
    // load Q tile, pre-scaled by 1/sqrt(hs)
#pragma unroll
    for (int i = 0; i < 2; ++i) {
        int f = tid + 256 * i;
        int r2 = f >> 4, cc = f & 15;
        float4 v = *(const float4*)&Qp[(size_t)(qt * 32 + r2) * HS + cc * 4];
        v.x *= 0.125f; v.y *= 0.125f; v.z *= 0.125f; v.w *= 0.125f;
        *(float4*)&Qs[r2][cc * 4] = v;
    }
    float m = -INFINITY, l = 0.f;
    float o[8] = {0.f, 0.f, 0.f, 0.f, 0.f, 0.f, 0.f, 0.f};
    const int qglob = qt * 32 + row;
    const int ntiles = (qt >> 1) + 1;
    for (int kt = 0; kt < ntiles; ++kt) {
        __syncthreads();   // prev PV done (and Qs ready on first iter)
#pragma unroll
        for (int i = 0; i < 4; ++i) {
            int f = tid + 256 * i;
            int r2 = f >> 4, cc = f & 15;
            *(float4*)&Ks[r2][cc * 4] = *(const float4*)&Kp[(size_t)(kt * 64 + r2) * HS + cc * 4];
            *(float4*)&Vs[r2][cc * 4] = *(const float4*)&Vp[(size_t)(kt * 64 + r2) * HS + cc * 4];
        }
        __syncthreads();
        float s[8];
#pragma unroll
        for (int c = 0; c < 8; ++c) s[c] = 0.f;
#pragma unroll 4
        for (int k4 = 0; k4 < 16; ++k4) {
            float4 qv = *(const float4*)&Qs[row][k4 * 4];
#pragma unroll
            for (int c8 = 0; c8 < 8; ++c8) {
                float4 kv = *(const float4*)&Ks[c8 * 8 + cq][k4 * 4];
                s[c8] += qv.x * kv.x + qv.y * kv.y + qv.z * kv.z + qv.w * kv.w;
            }
        }
        if (kt == ntiles - 1) {
#pragma unroll
            for (int c8 = 0; c8 < 8; ++c8) {
                int kg = kt * 64 + c8 * 8 + cq;
                if (kg > qglob) s[c8] = -INFINITY;
            }
        }
        float mx = s[0];
#pragma unroll
        for (int c = 1; c < 8; ++c) mx = fmaxf(mx, s[c]);
        mx = fmaxf(mx, __shfl_xor(mx, 1));
        mx = fmaxf(mx, __shfl_xor(mx, 2));
        mx = fmaxf(mx, __shfl_xor(mx, 4));
        float mnew = fmaxf(m, mx);
        float alpha = __expf(m - mnew);
        float rs = 0.f;
#pragma unroll
        for (int c8 = 0; c8 < 8; ++c8) {
            float p = __expf(s[c8] - mnew);
            Ps[row][c8 * 8 + cq] = p;
            rs += p;
        }
        rs += __shfl_xor(rs, 1);
        rs += __shfl_xor(rs, 2);
        rs += __shfl_xor(rs, 4);
        l = l * alpha + rs;
        m = mnew;
#pragma unroll
        for (int d = 0; d < 8; ++d) o[d] *= alpha;
        __syncthreads();   // Ps visible
#pragma unroll 8
        for (int k = 0; k < 64; ++k) {
            float p = Ps[row][k];
            float4 v0 = *(const float4*)&Vs[k][cq * 8 + 0];
            float4 v1 = *(const float4*)&Vs[k][cq * 8 + 4];
            o[0] += p * v0.x; o[1] += p * v0.y; o[2] += p * v0.z; o[3] += p * v0.w;
            o[4] += p * v1.x; o[5] += p * v1.y; o[6] += p * v1.z; o[7] += p * v1.w;
        }
    }
    float inv = 1.f / l;
    const int b = bh >> 4, h = bh & 15;
    float* yp = Y + ((size_t)b * TSEQ + qglob) * CEMB + h * HS + cq * 8;
    float4 w0 = make_float4(o[0] * inv, o[1] * inv, o[2] * inv, o[3] * inv);
    float4 w1 = make_float4(o[4] * inv, o[5] * inv, o[6] * inv, o[7] * inv);
    *(float4*)yp = w0;
    *(float4*)(yp + 4) = w1;
}

// ---------------- Output projection GEMM ----------------
__global__ __launch_bounds__(256) void proj_gemm_k(
    const float* __restrict__ A, const float* __restrict__ W,
    const float* __restrict__ bias, float* __restrict__ out)
{
    __shared__ float As[16][68];
    __shared__ float Bs[16][68];
    const int tid = threadIdx.x;
    const int n0 = blockIdx.x * 64;   // 0..1023
    const int m0 = blockIdx.y * 64;
    const int tm = tid >> 4, tn = tid & 15;
    const int lr = tid >> 2, lc = tid & 3;
    const int bk = tid >> 4, bc = tid & 15;
    const float* Arow = A + (size_t)(m0 + lr) * CEMB + lc * 4;
    const float* Brow = W + (size_t)bk * CEMB + n0 + bc * 4;
    float acc[4][4] = {};
    for (int k0 = 0; k0 < CEMB; k0 += 16) {
        float4 a = *(const float4*)(Arow + k0);
        As[lc * 4 + 0][lr] = a.x; As[lc * 4 + 1][lr] = a.y;
        As[lc * 4 + 2][lr] = a.z; As[lc * 4 + 3][lr] = a.w;
        *(float4*)&Bs[bk][bc * 4] = *(const float4*)(Brow + (size_t)k0 * CEMB);
        __syncthreads();
#pragma unroll
        for (int k = 0; k < 16; ++k) {
            float4 av = *(const float4*)&As[k][tm * 4];
            float4 bv = *(const float4*)&Bs[k][tn * 4];
            acc[0][0] += av.x * bv.x; acc[0][1] += av.x * bv.y;
            acc[0][2] += av.x * bv.z; acc[0][3] += av.x * bv.w;
            acc[1][0] += av.y * bv.x; acc[1][1] += av.y * bv.y;
            acc[1][2] += av.y * bv.z; acc[1][3] += av.y * bv.w;
            acc[2][0] += av.z * bv.x; acc[2][1] += av.z * bv.y;
            acc[2][2] += av.z * bv.z; acc[2][3] += av.z * bv.w;
            acc[3][0] += av.w * bv.x; acc[3][1] += av.w * bv.y;
            acc[3][2] += av.w * bv.z; acc[3][3] += av.w * bv.w;
        }
        __syncthreads();
    }
    const float b0 = bias[n0 + tn * 4 + 0], b1 = bias[n0 + tn * 4 + 1];
    const float b2 = bias[n0 + tn * 4 + 2], b3 = bias[n0 + tn * 4 + 3];
#pragma unroll
    for (int i = 0; i < 4; ++i) {
        int mrow = m0 + tm * 4 + i;
        float4 o;
        o.x = acc[i][0] + b0; o.y = acc[i][1] + b1;
        o.z = acc[i][2] + b2; o.w = acc[i][3] + b3;
        *(float4*)&out[(size_t)mrow * CEMB + n0 + tn * 4] = o;
    }
}

extern "C" void kernel_launch(void* const* d_in, const int* in_sizes, int n_in,
                              void* d_out, int out_size, void* d_ws, size_t ws_size,
                              hipStream_t stream)
{
    const float* x      = (const float*)d_in[0];
    const float* w_attn = (const float*)d_in[1];
    const float* b_attn = (const float*)d_in[2];
    const float* w_proj = (const float*)d_in[3];
    const float* b_proj = (const float*)d_in[4];
    float* out = (float*)d_out;
    float* ws  = (float*)d_ws;

    float* tbl = ws;                         // 1024 floats (16*32*2)
    float* Qd  = ws + 1024;                  // 4 Mi floats each
    float* Kd  = Qd + (size_t)4194304;
    float* Vd  = Kd + (size_t)4194304;
    float* Yd  = Vd + (size_t)4194304;       // attention output (B,T,C)

    rope_tbl_k<<<1, 512, 0, stream>>>(tbl);
    qkv_gemm_k<<<dim3(48, 64), 256, 0, stream>>>(x, w_attn, b_attn, tbl, Qd, Kd, Vd);
    attn_k<<<dim3(64, 32), 256, 0, stream>>>(Qd, Kd, Vd, Yd);
    proj_gemm_k<<<dim3(16, 64), 256, 0, stream>>>(Yd, w_proj, b_proj, out);
}

// Round 2
// 627.940 us; speedup vs baseline: 1.7412x; 1.7412x over previous
//
#include <hip/hip_runtime.h>
#include <hip/hip_bf16.h>
#include <math.h>

#define TSEQ 2048
#define CEMB 1024
#define NHEAD 16
#define HS 64

typedef __attribute__((ext_vector_type(8))) short bf16x8;
typedef __attribute__((ext_vector_type(4))) float f32x4;

// ---------------- RoPE table ----------------
// Reference quirk: _apply_rope uses cache[:d1] where d1 = n_head after the
// transpose, so the rotation angle is head_index * theta_j (constant over t).
__global__ void rope_tbl_k(float* __restrict__ tbl) {
    int i = blockIdx.x * blockDim.x + threadIdx.x;
    if (i >= NHEAD * 32) return;
    int h = i >> 5, j = i & 31;
    double theta = pow(10000.0, -2.0 * (double)j / 1024.0);
    double ang = (double)h * theta;
    tbl[2 * i + 0] = (float)cos(ang);
    tbl[2 * i + 1] = (float)sin(ang);
}

// ---------------- QKV GEMM + bias + RoPE epilogue (bf16 outputs) ----------------
// X: (4096, 1024), W: (1024, 3072). Tile 64x64, BK=16, 256 thr, 4x4 microtile.
// Q: bf16 (b,h,T,hs), rope'd, pre-scaled by 1/8. K: bf16 (b,h,T,hs), rope'd.
// V: bf16 TRANSPOSED (b,h,hs,T) so attention's PV B-fragment is a row read.
__global__ __launch_bounds__(256) void qkv_gemm_k(
    const float* __restrict__ X, const float* __restrict__ W,
    const float* __restrict__ bias, const float* __restrict__ tbl,
    __hip_bfloat16* __restrict__ Qb, __hip_bfloat16* __restrict__ Kb,
    __hip_bfloat16* __restrict__ Vtb)
{
    __shared__ float As[16][68];
    __shared__ float Bs[16][68];
    const int tid = threadIdx.x;
    const int n0 = blockIdx.x * 64;   // 0..3071
    const int m0 = blockIdx.y * 64;   // 0..4095
    const int tm = tid >> 4, tn = tid & 15;
    const int lr = tid >> 2, lc = tid & 3;    // A-load: row, k-float4
    const int bk = tid >> 4, bc = tid & 15;   // B-load: k, col-float4
    const float* Arow = X + (size_t)(m0 + lr) * CEMB + lc * 4;
    const float* Brow = W + (size_t)bk * (3 * CEMB) + n0 + bc * 4;
    float acc[4][4] = {};
    for (int k0 = 0; k0 < CEMB; k0 += 16) {
        float4 a = *(const float4*)(Arow + k0);
        As[lc * 4 + 0][lr] = a.x; As[lc * 4 + 1][lr] = a.y;
        As[lc * 4 + 2][lr] = a.z; As[lc * 4 + 3][lr] = a.w;
        *(float4*)&Bs[bk][bc * 4] = *(const float4*)(Brow + (size_t)k0 * (3 * CEMB));
        __syncthreads();
#pragma unroll
        for (int k = 0; k < 16; ++k) {
            float4 av = *(const float4*)&As[k][tm * 4];
            float4 bv = *(const float4*)&Bs[k][tn * 4];
            acc[0][0] += av.x * bv.x; acc[0][1] += av.x * bv.y;
            acc[0][2] += av.x * bv.z; acc[0][3] += av.x * bv.w;
            acc[1][0] += av.y * bv.x; acc[1][1] += av.y * bv.y;
            acc[1][2] += av.y * bv.z; acc[1][3] += av.y * bv.w;
            acc[2][0] += av.z * bv.x; acc[2][1] += av.z * bv.y;
            acc[2][2] += av.z * bv.z; acc[2][3] += av.z * bv.w;
            acc[3][0] += av.w * bv.x; acc[3][1] += av.w * bv.y;
            acc[3][2] += av.w * bv.z; acc[3][3] += av.w * bv.w;
        }
        __syncthreads();
    }
    const int sec = n0 >> 10;            // 0=q 1=k 2=v (uniform per block)
    const int h = (n0 & 1023) >> 6;      // uniform per block
    const int dbase = tn * 4;            // hs-dim base
    const int j0 = dbase >> 1;
    const float c0 = tbl[(h * 32 + j0) * 2 + 0], s0 = tbl[(h * 32 + j0) * 2 + 1];
    const float c1 = tbl[(h * 32 + j0 + 1) * 2 + 0], s1 = tbl[(h * 32 + j0 + 1) * 2 + 1];
    const float b0 = bias[n0 + dbase + 0], b1 = bias[n0 + dbase + 1];
    const float b2 = bias[n0 + dbase + 2], b3 = bias[n0 + dbase + 3];
#pragma unroll
    for (int i = 0; i < 4; ++i) {
        int mrow = m0 + tm * 4 + i;
        int bb = mrow >> 11, t = mrow & 2047;
        float v0 = acc[i][0] + b0, v1 = acc[i][1] + b1;
        float v2 = acc[i][2] + b2, v3 = acc[i][3] + b3;
        if (sec < 2) {
            float r0 = v0 * c0 - v1 * s0, r1 = v1 * c0 + v0 * s0;
            float r2 = v2 * c1 - v3 * s1, r3 = v3 * c1 + v2 * s1;
            float sc = (sec == 0) ? 0.125f : 1.0f;   // fold 1/sqrt(hs) into Q
            union { unsigned long long u; __hip_bfloat16 hh[4]; } pk;
            pk.hh[0] = __float2bfloat16(r0 * sc); pk.hh[1] = __float2bfloat16(r1 * sc);
            pk.hh[2] = __float2bfloat16(r2 * sc); pk.hh[3] = __float2bfloat16(r3 * sc);
            __hip_bfloat16* dst = (sec == 0) ? Qb : Kb;
            *(unsigned long long*)&dst[((size_t)(bb * NHEAD + h) * TSEQ + t) * HS + dbase] = pk.u;
        } else {
            // V transposed: (b,h,hs,T)
            size_t vb = ((size_t)(bb * NHEAD + h) * HS + dbase) * TSEQ + t;
            Vtb[vb + 0 * TSEQ] = __float2bfloat16(v0);
            Vtb[vb + 1 * TSEQ] = __float2bfloat16(v1);
            Vtb[vb + 2 * TSEQ] = __float2bfloat16(v2);
            Vtb[vb + 3 * TSEQ] = __float2bfloat16(v3);
        }
    }
}

// ---------------- Flash attention, bf16 MFMA ----------------
// Grid (32 qblk, 32 bh), 256 thr = 4 waves. Wave w owns q rows [qblk*64+w*16, +15].
// KV tile = 64. MFMA 16x16x32: A row=l&15,k=(l>>4)*8+i; B col=l&15; D col=l&15,row=(l>>4)*4+r.
__global__ __launch_bounds__(256) void attn_k(
    const __hip_bfloat16* __restrict__ Q, const __hip_bfloat16* __restrict__ K,
    const __hip_bfloat16* __restrict__ Vt, float* __restrict__ Y)
{
    __shared__ __hip_bfloat16 Ks[64][72];      // [kv][hs], +8 pad
    __shared__ __hip_bfloat16 Vs[64][72];      // [hs][kv], +8 pad
    __shared__ __hip_bfloat16 Ps[4][16][72];   // per-wave P tile [q][kv]
    const int tid = threadIdx.x;
    const int w = tid >> 6;
    const int lane = tid & 63;
    const int lr = lane & 15;
    const int lg = lane >> 4;
    const int qblk = blockIdx.x;
    const int bh = blockIdx.y;
    const size_t bho = (size_t)bh * TSEQ * HS;
    const int qw = qblk * 64 + w * 16;

    bf16x8 qa[2];
    {
        const __hip_bfloat16* qp = Q + bho + (size_t)(qw + lr) * HS + lg * 8;
        qa[0] = *(const bf16x8*)(qp);
        qa[1] = *(const bf16x8*)(qp + 32);
    }
    float mrow[4] = {-1e30f, -1e30f, -1e30f, -1e30f};
    float lsum[4] = {0.f, 0.f, 0.f, 0.f};
    f32x4 o[4] = {};   // [ht]: col = ht*16+lr, row(q) = qw + lg*4 + r

    for (int kt = 0; kt <= qblk; ++kt) {
        __syncthreads();   // everyone done reading prev K/Vs
        {
            const __hip_bfloat16* kg = K + bho + (size_t)kt * 64 * HS;
            const __hip_bfloat16* vg = Vt + bho + (size_t)kt * 64;
            int ch = tid;
#pragma unroll
            for (int rep = 0; rep < 2; ++rep, ch += 256) {
                int krow = ch >> 3, kc8 = (ch & 7) * 8;
                *(bf16x8*)&Ks[krow][kc8] = *(const bf16x8*)(kg + krow * HS + kc8);
                *(bf16x8*)&Vs[krow][kc8] = *(const bf16x8*)(vg + (size_t)krow * TSEQ + kc8);
            }
        }
        __syncthreads();
        // S = Q K^T  (Q pre-scaled)
        f32x4 s[4] = {};
#pragma unroll
        for (int ct = 0; ct < 4; ++ct) {
#pragma unroll
            for (int kb = 0; kb < 2; ++kb) {
                bf16x8 kf = *(const bf16x8*)&Ks[ct * 16 + lr][kb * 32 + lg * 8];
                s[ct] = __builtin_amdgcn_mfma_f32_16x16x32_bf16(qa[kb], kf, s[ct], 0, 0, 0);
            }
        }
        if (kt == qblk) {
#pragma unroll
            for (int ct = 0; ct < 4; ++ct) {
                int col = kt * 64 + ct * 16 + lr;
#pragma unroll
                for (int r = 0; r < 4; ++r) {
                    if (col > qw + lg * 4 + r) s[ct][r] = -1e30f;
                }
            }
        }
        // online softmax, per accumulator row r (q = qw + lg*4 + r)
#pragma unroll
        for (int r = 0; r < 4; ++r) {
            float mx = fmaxf(fmaxf(s[0][r], s[1][r]), fmaxf(s[2][r], s[3][r]));
            mx = fmaxf(mx, __shfl_xor(mx, 1));
            mx = fmaxf(mx, __shfl_xor(mx, 2));
            mx = fmaxf(mx, __shfl_xor(mx, 4));
            mx = fmaxf(mx, __shfl_xor(mx, 8));
            float mn = fmaxf(mrow[r], mx);
            float alpha = __expf(mrow[r] - mn);
            mrow[r] = mn;
            float rs = 0.f;
#pragma unroll
            for (int ct = 0; ct < 4; ++ct) {
                float p = __expf(s[ct][r] - mn);
                rs += p;
                Ps[w][lg * 4 + r][ct * 16 + lr] = __float2bfloat16(p);
            }
            rs += __shfl_xor(rs, 1);
            rs += __shfl_xor(rs, 2);
            rs += __shfl_xor(rs, 4);
            rs += __shfl_xor(rs, 8);
            lsum[r] = lsum[r] * alpha + rs;
            o[0][r] *= alpha; o[1][r] *= alpha; o[2][r] *= alpha; o[3][r] *= alpha;
        }
        // PV: wave-internal LDS RAW (DS ops are in-order within a wave)
#pragma unroll
        for (int kc = 0; kc < 2; ++kc) {
            bf16x8 pa = *(const bf16x8*)&Ps[w][lr][kc * 32 + lg * 8];
#pragma unroll
            for (int ht = 0; ht < 4; ++ht) {
                bf16x8 vb = *(const bf16x8*)&Vs[ht * 16 + lr][kc * 32 + lg * 8];
                o[ht] = __builtin_amdgcn_mfma_f32_16x16x32_bf16(pa, vb, o[ht], 0, 0, 0);
            }
        }
    }
    const int b = bh >> 4, h = bh & 15;
#pragma unroll
    for (int r = 0; r < 4; ++r) {
        float inv = 1.f / lsum[r];
        int q = qw + lg * 4 + r;
        float* yp = Y + ((size_t)b * TSEQ + q) * CEMB + h * HS + lr;
#pragma unroll
        for (int ht = 0; ht < 4; ++ht) yp[ht * 16] = o[ht][r] * inv;
    }
}

// ---------------- Output projection GEMM ----------------
__global__ __launch_bounds__(256) void proj_gemm_k(
    const float* __restrict__ A, const float* __restrict__ W,
    const float* __restrict__ bias, float* __restrict__ out)
{
    __shared__ float As[16][68];
    __shared__ float Bs[16][68];
    const int tid = threadIdx.x;
    const int n0 = blockIdx.x * 64;
    const int m0 = blockIdx.y * 64;
    const int tm = tid >> 4, tn = tid & 15;
    const int lr = tid >> 2, lc = tid & 3;
    const int bk = tid >> 4, bc = tid & 15;
    const float* Arow = A + (size_t)(m0 + lr) * CEMB + lc * 4;
    const float* Brow = W + (size_t)bk * CEMB + n0 + bc * 4;
    float acc[4][4] = {};
    for (int k0 = 0; k0 < CEMB; k0 += 16) {
        float4 a = *(const float4*)(Arow + k0);
        As[lc * 4 + 0][lr] = a.x; As[lc * 4 + 1][lr] = a.y;
        As[lc * 4 + 2][lr] = a.z; As[lc * 4 + 3][lr] = a.w;
        *(float4*)&Bs[bk][bc * 4] = *(const float4*)(Brow + (size_t)k0 * CEMB);
        __syncthreads();
#pragma unroll
        for (int k = 0; k < 16; ++k) {
            float4 av = *(const float4*)&As[k][tm * 4];
            float4 bv = *(const float4*)&Bs[k][tn * 4];
            acc[0][0] += av.x * bv.x; acc[0][1] += av.x * bv.y;
            acc[0][2] += av.x * bv.z; acc[0][3] += av.x * bv.w;
            acc[1][0] += av.y * bv.x; acc[1][1] += av.y * bv.y;
            acc[1][2] += av.y * bv.z; acc[1][3] += av.y * bv.w;
            acc[2][0] += av.z * bv.x; acc[2][1] += av.z * bv.y;
            acc[2][2] += av.z * bv.z; acc[2][3] += av.z * bv.w;
            acc[3][0] += av.w * bv.x; acc[3][1] += av.w * bv.y;
            acc[3][2] += av.w * bv.z; acc[3][3] += av.w * bv.w;
        }
        __syncthreads();
    }
    const float b0 = bias[n0 + tn * 4 + 0], b1 = bias[n0 + tn * 4 + 1];
    const float b2 = bias[n0 + tn * 4 + 2], b3 = bias[n0 + tn * 4 + 3];
#pragma unroll
    for (int i = 0; i < 4; ++i) {
        int mrow = m0 + tm * 4 + i;
        float4 o;
        o.x = acc[i][0] + b0; o.y = acc[i][1] + b1;
        o.z = acc[i][2] + b2; o.w = acc[i][3] + b3;
        *(float4*)&out[(size_t)mrow * CEMB + n0 + tn * 4] = o;
    }
}

extern "C" void kernel_launch(void* const* d_in, const int* in_sizes, int n_in,
                              void* d_out, int out_size, void* d_ws, size_t ws_size,
                              hipStream_t stream)
{
    const float* x      = (const float*)d_in[0];
    const float* w_attn = (const float*)d_in[1];
    const float* b_attn = (const float*)d_in[2];
    const float* w_proj = (const float*)d_in[3];
    const float* b_proj = (const float*)d_in[4];
    float* out = (float*)d_out;
    char* base = (char*)d_ws;

    float* tbl          = (float*)base;                              // 4 KB
    __hip_bfloat16* Qb  = (__hip_bfloat16*)(base + 4096);            // 8 MB
    __hip_bfloat16* Kb  = (__hip_bfloat16*)(base + 4096 + 8388608);  // 8 MB
    __hip_bfloat16* Vtb = (__hip_bfloat16*)(base + 4096 + 2 * 8388608); // 8 MB
    float* Yd           = (float*)(base + 4096 + 3 * 8388608);       // 16 MB

    rope_tbl_k<<<1, 512, 0, stream>>>(tbl);
    qkv_gemm_k<<<dim3(48, 64), 256, 0, stream>>>(x, w_attn, b_attn, tbl, Qb, Kb, Vtb);
    attn_k<<<dim3(32, 32), 256, 0, stream>>>(Qb, Kb, Vtb, Yd);
    proj_gemm_k<<<dim3(16, 64), 256, 0, stream>>>(Yd, w_proj, b_proj, out);
}

// Round 3
// 197.663 us; speedup vs baseline: 5.5314x; 3.1768x over previous
//
#include <hip/hip_runtime.h>
#include <hip/hip_bf16.h>
#include <math.h>

#define TSEQ 2048
#define CEMB 1024
#define NHEAD 16
#define HS 64

typedef __attribute__((ext_vector_type(8))) short bf16x8;
typedef __attribute__((ext_vector_type(4))) float f32x4;

__device__ __forceinline__ void gload16(const void* g, void* l) {
    __builtin_amdgcn_global_load_lds(
        (const __attribute__((address_space(1))) unsigned int*)g,
        (__attribute__((address_space(3))) unsigned int*)l, 16, 0, 0);
}

// ---------------- RoPE table ----------------
// Reference quirk: _apply_rope uses cache[:d1] where d1 = n_head after the
// transpose, so the rotation angle is head_index * theta_j (constant over t).
__global__ void rope_tbl_k(float* __restrict__ tbl) {
    int i = blockIdx.x * blockDim.x + threadIdx.x;
    if (i >= NHEAD * 32) return;
    int h = i >> 5, j = i & 31;
    double theta = pow(10000.0, -2.0 * (double)j / 1024.0);
    double ang = (double)h * theta;
    tbl[2 * i + 0] = (float)cos(ang);
    tbl[2 * i + 1] = (float)sin(ang);
}

// ---------------- fp32 -> bf16 convert (x) ----------------
__global__ __launch_bounds__(256) void cvt_bf16_k(const float* __restrict__ in,
                                                  __hip_bfloat16* __restrict__ out) {
    int i = (blockIdx.x * 256 + threadIdx.x) * 8;
    float4 a = *(const float4*)(in + i);
    float4 b = *(const float4*)(in + i + 4);
    union { bf16x8 v; __hip_bfloat16 h[8]; } pk;
    pk.h[0] = __float2bfloat16(a.x); pk.h[1] = __float2bfloat16(a.y);
    pk.h[2] = __float2bfloat16(a.z); pk.h[3] = __float2bfloat16(a.w);
    pk.h[4] = __float2bfloat16(b.x); pk.h[5] = __float2bfloat16(b.y);
    pk.h[6] = __float2bfloat16(b.z); pk.h[7] = __float2bfloat16(b.w);
    *(bf16x8*)(out + i) = pk.v;
}

// ---------------- transpose fp32 (K,N) -> bf16 (N,K) ----------------
__global__ __launch_bounds__(256) void transpose_bf16_k(const float* __restrict__ src,
                                                        __hip_bfloat16* __restrict__ dst,
                                                        int K, int N) {
    __shared__ float tile[32][33];
    int n0 = blockIdx.x * 32, k0 = blockIdx.y * 32;
    int tx = threadIdx.x & 31, ty = threadIdx.x >> 5;   // ty 0..7
#pragma unroll
    for (int i = 0; i < 32; i += 8)
        tile[ty + i][tx] = src[(size_t)(k0 + ty + i) * N + n0 + tx];
    __syncthreads();
#pragma unroll
    for (int i = 0; i < 32; i += 8)
        dst[(size_t)(n0 + ty + i) * K + k0 + tx] = __float2bfloat16(tile[tx][ty + i]);
}

// ---------------- QKV GEMM, bf16 MFMA, RoPE epilogue ----------------
// A = Xb (4096,1024) bf16 row-major; B = Wta (3072,1024) bf16 (pre-transposed).
// 128x128 tile, 4 waves (2x2), 4x4 16x16x32 frags, BK=32, global_load_lds w=16.
__global__ __launch_bounds__(256) void qkv_mfma_k(
    const __hip_bfloat16* __restrict__ Xb, const __hip_bfloat16* __restrict__ Wt,
    const float* __restrict__ bias, const float* __restrict__ tbl,
    __hip_bfloat16* __restrict__ Qb, __hip_bfloat16* __restrict__ Kb,
    __hip_bfloat16* __restrict__ Vtb)
{
    __shared__ __hip_bfloat16 Al[128 * 32];
    __shared__ __hip_bfloat16 Bl[128 * 32];
    const int tid = threadIdx.x;
    const int lane = tid & 63, w = tid >> 6;
    const int lr = lane & 15, lg = lane >> 4;
    const int wm = w >> 1, wn = w & 1;
    const int n0 = blockIdx.x * 128;   // 0..2944
    const int m0 = blockIdx.y * 128;   // 0..3968
    const __hip_bfloat16* gA = Xb + (size_t)(m0 + (tid >> 2)) * CEMB + (tid & 3) * 8;
    const __hip_bfloat16* gB = Wt + (size_t)(n0 + (tid >> 2)) * CEMB + (tid & 3) * 8;
    __hip_bfloat16* lA = &Al[tid * 8];
    __hip_bfloat16* lB = &Bl[tid * 8];
    f32x4 acc[4][4] = {};
    for (int k0 = 0; k0 < CEMB; k0 += 32) {
        if (k0) __syncthreads();
        gload16(gA + k0, lA);
        gload16(gA + 64 * CEMB + k0, lA + 2048);
        gload16(gB + k0, lB);
        gload16(gB + 64 * CEMB + k0, lB + 2048);
        __syncthreads();
        bf16x8 af[4], bfr[4];
#pragma unroll
        for (int mi = 0; mi < 4; ++mi)
            af[mi] = *(const bf16x8*)&Al[(wm * 64 + mi * 16 + lr) * 32 + lg * 8];
#pragma unroll
        for (int ni = 0; ni < 4; ++ni)
            bfr[ni] = *(const bf16x8*)&Bl[(wn * 64 + ni * 16 + lr) * 32 + lg * 8];
#pragma unroll
        for (int mi = 0; mi < 4; ++mi)
#pragma unroll
            for (int ni = 0; ni < 4; ++ni)
                acc[mi][ni] = __builtin_amdgcn_mfma_f32_16x16x32_bf16(af[mi], bfr[ni], acc[mi][ni], 0, 0, 0);
    }
    // epilogue: bias + rope + scatter. sec/bb uniform per block.
    const int sec = (n0 >> 10);
#pragma unroll
    for (int mi = 0; mi < 4; ++mi) {
#pragma unroll
        for (int ni = 0; ni < 4; ++ni) {
            const int gcol = n0 + wn * 64 + ni * 16 + lr;
            const int c63 = gcol & 63;
            const int h = (gcol & 1023) >> 6;
            const int j = c63 >> 1;
            const float cth = tbl[(h * 32 + j) * 2 + 0];
            const float sth = tbl[(h * 32 + j) * 2 + 1];
            const float bv = bias[gcol];
            const int growb = m0 + wm * 64 + mi * 16 + lg * 4;
            const int bb = growb >> 11;
            const int t0 = growb & 2047;
            if (sec == 2) {
                union { unsigned long long u; __hip_bfloat16 hh[4]; } pk;
#pragma unroll
                for (int r = 0; r < 4; ++r) pk.hh[r] = __float2bfloat16(acc[mi][ni][r] + bv);
                *(unsigned long long*)&Vtb[(((size_t)bb * NHEAD + h) * HS + c63) * TSEQ + t0] = pk.u;
            } else {
                const float sc = (sec == 0) ? 0.125f : 1.0f;
                __hip_bfloat16* dst = (sec == 0) ? Qb : Kb;
#pragma unroll
                for (int r = 0; r < 4; ++r) {
                    float val = acc[mi][ni][r] + bv;
                    float prt = __shfl_xor(val, 1);
                    float rot = (lr & 1) ? (val * cth + prt * sth) : (val * cth - prt * sth);
                    dst[(((size_t)bb * NHEAD + h) * TSEQ + t0 + r) * HS + c63] = __float2bfloat16(rot * sc);
                }
            }
        }
    }
}

// ---------------- Flash attention, bf16 MFMA (bf16 Y out) ----------------
__global__ __launch_bounds__(256) void attn_k(
    const __hip_bfloat16* __restrict__ Q, const __hip_bfloat16* __restrict__ K,
    const __hip_bfloat16* __restrict__ Vt, __hip_bfloat16* __restrict__ Y)
{
    __shared__ __hip_bfloat16 Ks[64][72];
    __shared__ __hip_bfloat16 Vs[64][72];
    __shared__ __hip_bfloat16 Ps[4][16][72];
    const int tid = threadIdx.x;
    const int w = tid >> 6;
    const int lane = tid & 63;
    const int lr = lane & 15;
    const int lg = lane >> 4;
    const int qblk = blockIdx.x;
    const int bh = blockIdx.y;
    const size_t bho = (size_t)bh * TSEQ * HS;
    const int qw = qblk * 64 + w * 16;

    bf16x8 qa[2];
    {
        const __hip_bfloat16* qp = Q + bho + (size_t)(qw + lr) * HS + lg * 8;
        qa[0] = *(const bf16x8*)(qp);
        qa[1] = *(const bf16x8*)(qp + 32);
    }
    float mrow[4] = {-1e30f, -1e30f, -1e30f, -1e30f};
    float lsum[4] = {0.f, 0.f, 0.f, 0.f};
    f32x4 o[4] = {};

    for (int kt = 0; kt <= qblk; ++kt) {
        __syncthreads();
        {
            const __hip_bfloat16* kg = K + bho + (size_t)kt * 64 * HS;
            const __hip_bfloat16* vg = Vt + bho + (size_t)kt * 64;
            int ch = tid;
#pragma unroll
            for (int rep = 0; rep < 2; ++rep, ch += 256) {
                int krow = ch >> 3, kc8 = (ch & 7) * 8;
                *(bf16x8*)&Ks[krow][kc8] = *(const bf16x8*)(kg + krow * HS + kc8);
                *(bf16x8*)&Vs[krow][kc8] = *(const bf16x8*)(vg + (size_t)krow * TSEQ + kc8);
            }
        }
        __syncthreads();
        f32x4 s[4] = {};
#pragma unroll
        for (int ct = 0; ct < 4; ++ct) {
#pragma unroll
            for (int kb = 0; kb < 2; ++kb) {
                bf16x8 kf = *(const bf16x8*)&Ks[ct * 16 + lr][kb * 32 + lg * 8];
                s[ct] = __builtin_amdgcn_mfma_f32_16x16x32_bf16(qa[kb], kf, s[ct], 0, 0, 0);
            }
        }
        if (kt == qblk) {
#pragma unroll
            for (int ct = 0; ct < 4; ++ct) {
                int col = kt * 64 + ct * 16 + lr;
#pragma unroll
                for (int r = 0; r < 4; ++r) {
                    if (col > qw + lg * 4 + r) s[ct][r] = -1e30f;
                }
            }
        }
#pragma unroll
        for (int r = 0; r < 4; ++r) {
            float mx = fmaxf(fmaxf(s[0][r], s[1][r]), fmaxf(s[2][r], s[3][r]));
            mx = fmaxf(mx, __shfl_xor(mx, 1));
            mx = fmaxf(mx, __shfl_xor(mx, 2));
            mx = fmaxf(mx, __shfl_xor(mx, 4));
            mx = fmaxf(mx, __shfl_xor(mx, 8));
            float mn = fmaxf(mrow[r], mx);
            float alpha = __expf(mrow[r] - mn);
            mrow[r] = mn;
            float rs = 0.f;
#pragma unroll
            for (int ct = 0; ct < 4; ++ct) {
                float p = __expf(s[ct][r] - mn);
                rs += p;
                Ps[w][lg * 4 + r][ct * 16 + lr] = __float2bfloat16(p);
            }
            rs += __shfl_xor(rs, 1);
            rs += __shfl_xor(rs, 2);
            rs += __shfl_xor(rs, 4);
            rs += __shfl_xor(rs, 8);
            lsum[r] = lsum[r] * alpha + rs;
            o[0][r] *= alpha; o[1][r] *= alpha; o[2][r] *= alpha; o[3][r] *= alpha;
        }
#pragma unroll
        for (int kc = 0; kc < 2; ++kc) {
            bf16x8 pa = *(const bf16x8*)&Ps[w][lr][kc * 32 + lg * 8];
#pragma unroll
            for (int ht = 0; ht < 4; ++ht) {
                bf16x8 vb = *(const bf16x8*)&Vs[ht * 16 + lr][kc * 32 + lg * 8];
                o[ht] = __builtin_amdgcn_mfma_f32_16x16x32_bf16(pa, vb, o[ht], 0, 0, 0);
            }
        }
    }
    const int b = bh >> 4, h = bh & 15;
#pragma unroll
    for (int r = 0; r < 4; ++r) {
        float inv = 1.f / lsum[r];
        int q = qw + lg * 4 + r;
        __hip_bfloat16* yp = Y + ((size_t)b * TSEQ + q) * CEMB + h * HS + lr;
#pragma unroll
        for (int ht = 0; ht < 4; ++ht) yp[ht * 16] = __float2bfloat16(o[ht][r] * inv);
    }
}

// ---------------- Output projection, bf16 MFMA ----------------
__global__ __launch_bounds__(256) void proj_mfma_k(
    const __hip_bfloat16* __restrict__ Ab, const __hip_bfloat16* __restrict__ Wt,
    const float* __restrict__ bias, float* __restrict__ out)
{
    __shared__ __hip_bfloat16 Al[128 * 32];
    __shared__ __hip_bfloat16 Bl[128 * 32];
    const int tid = threadIdx.x;
    const int lane = tid & 63, w = tid >> 6;
    const int lr = lane & 15, lg = lane >> 4;
    const int wm = w >> 1, wn = w & 1;
    const int n0 = blockIdx.x * 128;
    const int m0 = blockIdx.y * 128;
    const __hip_bfloat16* gA = Ab + (size_t)(m0 + (tid >> 2)) * CEMB + (tid & 3) * 8;
    const __hip_bfloat16* gB = Wt + (size_t)(n0 + (tid >> 2)) * CEMB + (tid & 3) * 8;
    __hip_bfloat16* lA = &Al[tid * 8];
    __hip_bfloat16* lB = &Bl[tid * 8];
    f32x4 acc[4][4] = {};
    for (int k0 = 0; k0 < CEMB; k0 += 32) {
        if (k0) __syncthreads();
        gload16(gA + k0, lA);
        gload16(gA + 64 * CEMB + k0, lA + 2048);
        gload16(gB + k0, lB);
        gload16(gB + 64 * CEMB + k0, lB + 2048);
        __syncthreads();
        bf16x8 af[4], bfr[4];
#pragma unroll
        for (int mi = 0; mi < 4; ++mi)
            af[mi] = *(const bf16x8*)&Al[(wm * 64 + mi * 16 + lr) * 32 + lg * 8];
#pragma unroll
        for (int ni = 0; ni < 4; ++ni)
            bfr[ni] = *(const bf16x8*)&Bl[(wn * 64 + ni * 16 + lr) * 32 + lg * 8];
#pragma unroll
        for (int mi = 0; mi < 4; ++mi)
#pragma unroll
            for (int ni = 0; ni < 4; ++ni)
                acc[mi][ni] = __builtin_amdgcn_mfma_f32_16x16x32_bf16(af[mi], bfr[ni], acc[mi][ni], 0, 0, 0);
    }
#pragma unroll
    for (int mi = 0; mi < 4; ++mi) {
#pragma unroll
        for (int ni = 0; ni < 4; ++ni) {
            const int gcol = n0 + wn * 64 + ni * 16 + lr;
            const float bv = bias[gcol];
            const int growb = m0 + wm * 64 + mi * 16 + lg * 4;
#pragma unroll
            for (int r = 0; r < 4; ++r)
                out[(size_t)(growb + r) * CEMB + gcol] = acc[mi][ni][r] + bv;
        }
    }
}

extern "C" void kernel_launch(void* const* d_in, const int* in_sizes, int n_in,
                              void* d_out, int out_size, void* d_ws, size_t ws_size,
                              hipStream_t stream)
{
    const float* x      = (const float*)d_in[0];
    const float* w_attn = (const float*)d_in[1];
    const float* b_attn = (const float*)d_in[2];
    const float* w_proj = (const float*)d_in[3];
    const float* b_proj = (const float*)d_in[4];
    float* out = (float*)d_out;
    char* base = (char*)d_ws;

    const size_t MB = 1048576;
    float* tbl          = (float*)base;                         // 4 KB
    __hip_bfloat16* Xb  = (__hip_bfloat16*)(base + 4096);       // 8 MB (reused as Yb)
    __hip_bfloat16* Wta = (__hip_bfloat16*)(base + 4096 + 8 * MB);   // 6 MB
    __hip_bfloat16* Wpt = (__hip_bfloat16*)(base + 4096 + 14 * MB);  // 2 MB
    __hip_bfloat16* Qb  = (__hip_bfloat16*)(base + 4096 + 16 * MB);  // 8 MB
    __hip_bfloat16* Kb  = (__hip_bfloat16*)(base + 4096 + 24 * MB);  // 8 MB
    __hip_bfloat16* Vtb = (__hip_bfloat16*)(base + 4096 + 32 * MB);  // 8 MB
    __hip_bfloat16* Yb  = Xb;   // x no longer needed after qkv GEMM

    rope_tbl_k<<<1, 512, 0, stream>>>(tbl);
    cvt_bf16_k<<<2048, 256, 0, stream>>>(x, Xb);
    transpose_bf16_k<<<dim3(96, 32), 256, 0, stream>>>(w_attn, Wta, CEMB, 3 * CEMB);
    transpose_bf16_k<<<dim3(32, 32), 256, 0, stream>>>(w_proj, Wpt, CEMB, CEMB);
    qkv_mfma_k<<<dim3(24, 32), 256, 0, stream>>>(Xb, Wta, b_attn, tbl, Qb, Kb, Vtb);
    attn_k<<<dim3(32, 32), 256, 0, stream>>>(Qb, Kb, Vtb, Yb);
    proj_mfma_k<<<dim3(8, 32), 256, 0, stream>>>(Yb, Wpt, b_proj, out);
}